// Round 2
// baseline (2282.486 us; speedup 1.0000x reference)
//
#include <hip/hip_runtime.h>
#include <math.h>

#define N_ROWS   16384
#define DIM      512
#define DQV      128          // DIM/4 float4s per row
#define K_CODES  8192
#define BM       64           // rows per block
#define BK       512          // codes per strip
#define BD       8            // d-chunk per E tile
#define THREADS  256
#define XS_LD    68           // 64 rows + 4 pad (keeps 16B alignment for b128)

#define OUT_LOSS 8388608
#define OUT_PERP 8388609
#define OUT_IDX  8388610

__global__ void init_ws(double* ws_loss, int* ws_maxidx) {
    *ws_loss = 0.0;
    *ws_maxidx = 0;
}

// ---- numpy pairwise-sum emulation of xx[n] = np.sum(flat**2, axis=1) ----
// n=512: split 256+256 -> 128+128 -> 8-accumulator unrolled base case.
// All ops via __fmul_rn/__fadd_rn so -ffp-contract can't fuse or reorder.
__device__ __forceinline__ float p128_sq(const float4* p) {
    float4 q0 = p[0], q1 = p[1];
    float r0 = __fmul_rn(q0.x, q0.x), r1 = __fmul_rn(q0.y, q0.y);
    float r2 = __fmul_rn(q0.z, q0.z), r3 = __fmul_rn(q0.w, q0.w);
    float r4 = __fmul_rn(q1.x, q1.x), r5 = __fmul_rn(q1.y, q1.y);
    float r6 = __fmul_rn(q1.z, q1.z), r7 = __fmul_rn(q1.w, q1.w);
    #pragma unroll
    for (int t = 1; t < 16; ++t) {
        q0 = p[2 * t]; q1 = p[2 * t + 1];
        r0 = __fadd_rn(r0, __fmul_rn(q0.x, q0.x));
        r1 = __fadd_rn(r1, __fmul_rn(q0.y, q0.y));
        r2 = __fadd_rn(r2, __fmul_rn(q0.z, q0.z));
        r3 = __fadd_rn(r3, __fmul_rn(q0.w, q0.w));
        r4 = __fadd_rn(r4, __fmul_rn(q1.x, q1.x));
        r5 = __fadd_rn(r5, __fmul_rn(q1.y, q1.y));
        r6 = __fadd_rn(r6, __fmul_rn(q1.z, q1.z));
        r7 = __fadd_rn(r7, __fmul_rn(q1.w, q1.w));
    }
    return __fadd_rn(__fadd_rn(__fadd_rn(r0, r1), __fadd_rn(r2, r3)),
                     __fadd_rn(__fadd_rn(r4, r5), __fadd_rn(r6, r7)));
}

__global__ __launch_bounds__(256) void xx_kernel(const float4* __restrict__ x4,
                                                 float* __restrict__ xx) {
    int row = blockIdx.x * 256 + threadIdx.x;
    const float4* p = x4 + (size_t)row * DQV;
    float a = p128_sq(p);
    float b = p128_sq(p + 32);
    float c = p128_sq(p + 64);
    float d = p128_sq(p + 96);
    xx[row] = __fadd_rn(__fadd_rn(a, b), __fadd_rn(c, d));
}

__global__ __launch_bounds__(THREADS) void vq_main(const float* __restrict__ x,
                                                   const float* __restrict__ emb,
                                                   const float* __restrict__ xx,
                                                   float* __restrict__ out,
                                                   double* __restrict__ ws_loss,
                                                   int* __restrict__ ws_maxidx) {
    // Static LDS: 139264 + 16384 + 256 = 155904 B (<= 160 KiB on gfx950)
    __shared__ float Xs[DIM * XS_LD];     // x tile, transposed [d][row]
    __shared__ float EsU[BD * BK];        // E tile [dd][code]; reused as argmin red buf
    __shared__ int   idxRow[BM];

    const int tid = threadIdx.x;
    const int tx  = tid & 31;             // code group
    const int ty  = tid >> 5;             // row group 0..7
    const int r0  = blockIdx.x * BM;

    const float4* x4   = (const float4*)x;
    const float4* emb4 = (const float4*)emb;
    float4*       out4 = (float4*)out;

    // ---- stage X transposed (one-time) ----
    for (int i = tid; i < BM * DQV; i += THREADS) {
        int r = i >> 7, dq = i & 127;
        float4 v = x4[(size_t)(r0 + r) * DQV + dq];
        int d = dq * 4;
        Xs[(d + 0) * XS_LD + r] = v.x;
        Xs[(d + 1) * XS_LD + r] = v.y;
        Xs[(d + 2) * XS_LD + r] = v.z;
        Xs[(d + 3) * XS_LD + r] = v.w;
    }

    // per-thread row norms (ref semantics: d = fl(xx - 2*dot); ee vanishes in fp32)
    float xrow[8];
    #pragma unroll
    for (int i = 0; i < 8; ++i) xrow[i] = xx[r0 + 8 * ty + i];

    float bestv[8];
    int   besti[8];
    #pragma unroll
    for (int i = 0; i < 8; ++i) { bestv[i] = 3.402823466e38f; besti[i] = 0; }

    const int c0 = tid;        // staging code ids within strip
    const int c1 = tid + 256;

    for (int kc = 0; kc < K_CODES / BK; ++kc) {
        const int k0 = kc * BK;
        float acc[8][16];
        #pragma unroll
        for (int i = 0; i < 8; ++i)
            #pragma unroll
            for (int j = 0; j < 16; ++j) acc[i][j] = 0.0f;

        // prefetch tile dc=0
        float4 p0 = emb4[(size_t)(k0 + c0) * DQV + 0];
        float4 p1 = emb4[(size_t)(k0 + c0) * DQV + 1];
        float4 p2 = emb4[(size_t)(k0 + c1) * DQV + 0];
        float4 p3 = emb4[(size_t)(k0 + c1) * DQV + 1];

        for (int dc = 0; dc < DIM / BD; ++dc) {
            __syncthreads();   // previous tile fully consumed
            EsU[0 * BK + c0] = p0.x; EsU[1 * BK + c0] = p0.y;
            EsU[2 * BK + c0] = p0.z; EsU[3 * BK + c0] = p0.w;
            EsU[4 * BK + c0] = p1.x; EsU[5 * BK + c0] = p1.y;
            EsU[6 * BK + c0] = p1.z; EsU[7 * BK + c0] = p1.w;
            EsU[0 * BK + c1] = p2.x; EsU[1 * BK + c1] = p2.y;
            EsU[2 * BK + c1] = p2.z; EsU[3 * BK + c1] = p2.w;
            EsU[4 * BK + c1] = p3.x; EsU[5 * BK + c1] = p3.y;
            EsU[6 * BK + c1] = p3.z; EsU[7 * BK + c1] = p3.w;
            __syncthreads();

            if (dc + 1 < DIM / BD) {   // prefetch next tile
                int dq = 2 * (dc + 1);
                p0 = emb4[(size_t)(k0 + c0) * DQV + dq];
                p1 = emb4[(size_t)(k0 + c0) * DQV + dq + 1];
                p2 = emb4[(size_t)(k0 + c1) * DQV + dq];
                p3 = emb4[(size_t)(k0 + c1) * DQV + dq + 1];
            }

            const int dbase = dc * BD;
            // k-sequential fp32 FMA chain per (row,code) — matches BLAS GEBP
            // (one accumulator per C element, k ascending).
            #pragma unroll
            for (int dd = 0; dd < BD; ++dd) {
                const float* xp = &Xs[(dbase + dd) * XS_LD + 8 * ty];
                float4 xa = *(const float4*)(xp);
                float4 xb = *(const float4*)(xp + 4);
                const float* ep = &EsU[dd * BK + 4 * tx];
                float4 e0 = *(const float4*)(ep);
                float4 e1 = *(const float4*)(ep + 128);
                float4 e2 = *(const float4*)(ep + 256);
                float4 e3 = *(const float4*)(ep + 384);
                float xv[8]  = {xa.x, xa.y, xa.z, xa.w, xb.x, xb.y, xb.z, xb.w};
                float ev[16] = {e0.x, e0.y, e0.z, e0.w, e1.x, e1.y, e1.z, e1.w,
                                e2.x, e2.y, e2.z, e2.w, e3.x, e3.y, e3.z, e3.w};
                #pragma unroll
                for (int i = 0; i < 8; ++i)
                    #pragma unroll
                    for (int j = 0; j < 16; ++j)
                        acc[i][j] = __fmaf_rn(xv[i], ev[j], acc[i][j]);
            }
        }

        // ref fp32 score: s = fl(xx - 2*dot)  (single rounding, == fp32 subtract
        // of exact 2*dot). Ties collapse into ulp-bins; strict < keeps lowest code.
        #pragma unroll
        for (int i = 0; i < 8; ++i) {
            #pragma unroll
            for (int j = 0; j < 4; ++j) {
                #pragma unroll
                for (int l = 0; l < 4; ++l) {
                    float s = __fmaf_rn(-2.0f, acc[i][4 * j + l], xrow[i]);
                    int code = k0 + 128 * j + 4 * tx + l;
                    if (s < bestv[i]) { bestv[i] = s; besti[i] = code; }
                }
            }
        }
    }

    // ---- cross-thread argmin reduction (reuse EsU) ----
    __syncthreads();
    float* redv = EsU;                    // [64][32]
    int*   redi = (int*)(EsU + 2048);     // [64][32]
    #pragma unroll
    for (int i = 0; i < 8; ++i) {
        int row = 8 * ty + i;
        redv[row * 32 + tx] = bestv[i];
        redi[row * 32 + tx] = besti[i];
    }
    __syncthreads();
    if (tid < BM) {
        int row = tid;
        float v  = redv[row * 32];
        int  idx = redi[row * 32];
        for (int t = 1; t < 32; ++t) {
            float vv = redv[row * 32 + t];
            int   ii = redi[row * 32 + t];
            if (vv < v || (vv == v && ii < idx)) { v = vv; idx = ii; }
        }
        idxRow[row] = idx;
        out[OUT_IDX + r0 + row] = (float)idx;
        atomicMax(ws_maxidx, idx);
    }
    __syncthreads();

    // ---- gather quantized, straight-through output, loss partial ----
    double lsum = 0.0;
    for (int i = tid; i < BM * DQV; i += THREADS) {
        int row = i >> 7, dq = i & 127;
        int ki  = idxRow[row];
        float4 q = emb4[(size_t)ki * DQV + dq];
        int d = dq * 4;
        float xv0 = Xs[(d + 0) * XS_LD + row];
        float xv1 = Xs[(d + 1) * XS_LD + row];
        float xv2 = Xs[(d + 2) * XS_LD + row];
        float xv3 = Xs[(d + 3) * XS_LD + row];
        float d0 = q.x - xv0, d1 = q.y - xv1, d2 = q.z - xv2, d3 = q.w - xv3;
        lsum += (double)d0 * (double)d0 + (double)d1 * (double)d1
              + (double)d2 * (double)d2 + (double)d3 * (double)d3;
        float4 o;
        o.x = xv0 + d0; o.y = xv1 + d1; o.z = xv2 + d2; o.w = xv3 + d3;
        out4[(size_t)(r0 + row) * DQV + dq] = o;
    }
    #pragma unroll
    for (int off = 32; off > 0; off >>= 1) lsum += __shfl_down(lsum, off);
    if ((tid & 63) == 0) atomicAdd(ws_loss, lsum);
}

__global__ void vq_final(const double* __restrict__ ws_loss,
                         const int* __restrict__ ws_maxidx,
                         float* __restrict__ out) {
    if (threadIdx.x == 0) {
        double mean = *ws_loss / (double)((size_t)N_ROWS * DIM);
        out[OUT_LOSS] = (float)(1.25 * mean);   // q_latent + 0.25*e_latent
        double L   = (double)(*ws_maxidx + 1);
        double avg = 1.0 / L;
        out[OUT_PERP] = (float)exp(-avg * log(avg + 1e-10));
    }
}

extern "C" void kernel_launch(void* const* d_in, const int* in_sizes, int n_in,
                              void* d_out, int out_size, void* d_ws, size_t ws_size,
                              hipStream_t stream) {
    const float* x   = (const float*)d_in[0];
    const float* emb = (const float*)d_in[1];
    float* out = (float*)d_out;

    float*  xx        = (float*)d_ws;                       // 16384 floats
    double* ws_loss   = (double*)((char*)d_ws + 65536);
    int*    ws_maxidx = (int*)((char*)d_ws + 65544);

    hipLaunchKernelGGL(init_ws, dim3(1), dim3(1), 0, stream, ws_loss, ws_maxidx);
    hipLaunchKernelGGL(xx_kernel, dim3(N_ROWS / 256), dim3(256), 0, stream,
                       (const float4*)x, xx);
    hipLaunchKernelGGL(vq_main, dim3(N_ROWS / BM), dim3(THREADS), 0, stream,
                       x, emb, xx, out, ws_loss, ws_maxidx);
    hipLaunchKernelGGL(vq_final, dim3(1), dim3(64), 0, stream,
                       ws_loss, ws_maxidx, out);
}